// Round 1
// baseline (761.621 us; speedup 1.0000x reference)
//
#include <hip/hip_runtime.h>
#include <math.h>

#define N 4096
#define D 128
#define EPSV 1e-8f

__device__ __forceinline__ float lrelu(float x){ return x > 0.f ? x : 0.2f*x; }

__device__ __forceinline__ float wave_sum(float v){
  #pragma unroll
  for (int off = 32; off; off >>= 1) v += __shfl_down(v, off);
  return v;
}
__device__ __forceinline__ float wave_max(float v){
  #pragma unroll
  for (int off = 32; off; off >>= 1) v = fmaxf(v, __shfl_down(v, off));
  return v;
}
// block of 256 threads (4 waves)
__device__ __forceinline__ float block_sum256(float v, float* red){
  v = wave_sum(v);
  if ((threadIdx.x & 63) == 0) red[threadIdx.x >> 6] = v;
  __syncthreads();
  float r = (red[0] + red[1]) + (red[2] + red[3]);
  __syncthreads();
  return r;
}
__device__ __forceinline__ float block_max256(float v, float* red){
  v = wave_max(v);
  if ((threadIdx.x & 63) == 0) red[threadIdx.x >> 6] = v;
  __syncthreads();
  float r = fmaxf(fmaxf(red[0], red[1]), fmaxf(red[2], red[3]));
  __syncthreads();
  return r;
}

// dis[i] = 1/sqrt(sum_j adj[i][j] + 1e-8)
__global__ void k_rowsum(const float* __restrict__ adj, float* __restrict__ dis){
  int i = blockIdx.x;
  const float4* row = reinterpret_cast<const float4*>(adj + (size_t)i * N);
  float s = 0.f;
  #pragma unroll
  for (int l = 0; l < 4; ++l){
    float4 v = row[threadIdx.x + l * 256];
    s += (v.x + v.y) + (v.z + v.w);
  }
  __shared__ float red[4];
  s = block_sum256(s, red);
  if (threadIdx.x == 0) dis[i] = 1.0f / sqrtf(s + EPSV);
}

// u = h @ W ; p = h @ a_src ; q = h @ a_dst   (block = 128 threads, one row)
__global__ void k_uhat(const float* __restrict__ h, const float* __restrict__ W,
                       const float* __restrict__ aa, float* __restrict__ u,
                       float* __restrict__ p, float* __restrict__ q){
  int i = blockIdx.x, t = threadIdx.x;
  __shared__ float hs[D];
  __shared__ float red[4];
  float hv = h[(size_t)i * D + t];
  hs[t] = hv;
  __syncthreads();
  float acc = 0.f;
  #pragma unroll 8
  for (int k = 0; k < D; ++k) acc = fmaf(hs[k], W[k * D + t], acc);
  u[(size_t)i * D + t] = acc;
  float pv = hv * aa[t];
  float qv = hv * aa[D + t];
  pv = wave_sum(pv); qv = wave_sum(qv);
  if ((t & 63) == 0){ red[t >> 6] = pv; red[2 + (t >> 6)] = qv; }
  __syncthreads();
  if (t == 0){ p[i] = red[0] + red[1]; q[i] = red[2] + red[3]; }
}

// Row max + sum(exp) stats. MODE 0: src=adj with d_i d_j norm. MODE 1: src=b.
// MODE 2: src=b, plus attention-row stats from p,q.
template<int MODE>
__global__ void k_stats(const float* __restrict__ src, const float* __restrict__ dis,
                        const float* __restrict__ pv, const float* __restrict__ qv,
                        float* __restrict__ mb, float* __restrict__ lb,
                        float* __restrict__ ma, float* __restrict__ la){
  __shared__ float red[4];
  int i = blockIdx.x;
  const float4* src4 = reinterpret_cast<const float4*>(src + (size_t)i * N);
  const float4* dis4 = reinterpret_cast<const float4*>(dis);
  const float4* q4   = reinterpret_cast<const float4*>(qv);
  float di = (MODE == 0) ? dis[i] : 0.f;
  float pi = (MODE == 2) ? pv[i] : 0.f;
  float4 vals[4];
  float mx = -3.4e38f, amx = -3.4e38f;
  #pragma unroll
  for (int l = 0; l < 4; ++l){
    int t = threadIdx.x + l * 256;
    float4 a = src4[t];
    if (MODE == 0){
      float4 dj = dis4[t];
      a.x *= di * dj.x; a.y *= di * dj.y; a.z *= di * dj.z; a.w *= di * dj.w;
    }
    vals[l] = a;
    mx = fmaxf(mx, fmaxf(fmaxf(a.x, a.y), fmaxf(a.z, a.w)));
    if (MODE == 2){
      float4 qq = q4[t];
      float a0 = lrelu(pi + qq.x), a1 = lrelu(pi + qq.y);
      float a2 = lrelu(pi + qq.z), a3 = lrelu(pi + qq.w);
      amx = fmaxf(amx, fmaxf(fmaxf(a0, a1), fmaxf(a2, a3)));
    }
  }
  float m = block_max256(mx, red);
  float se = 0.f;
  #pragma unroll
  for (int l = 0; l < 4; ++l){
    float4 a = vals[l];
    se += expf(a.x - m) + expf(a.y - m) + expf(a.z - m) + expf(a.w - m);
  }
  float ls = block_sum256(se, red);
  if (MODE == 2){
    float am = block_max256(amx, red);
    float ase = 0.f;
    #pragma unroll
    for (int l = 0; l < 4; ++l){
      int t = threadIdx.x + l * 256;
      float4 qq = q4[t];
      ase += expf(lrelu(pi + qq.x) - am) + expf(lrelu(pi + qq.y) - am)
           + expf(lrelu(pi + qq.z) - am) + expf(lrelu(pi + qq.w) - am);
    }
    float al = block_sum256(ase, red);
    if (threadIdx.x == 0){ ma[i] = am; la[i] = al; }
  }
  if (threadIdx.x == 0){ mb[i] = m; lb[i] = ls; }
}

// s[i][n] = sum_j softmax_row(i)[j] * u[j][n], softmax applied on the fly from (mb,lb).
// MODE 0: logits = d_i d_j adj. MODE 1: logits = b. MODE 2: 0.6*softmax(b) + 0.4*softmax(attn).
// Block: 256 threads, 8 rows x 128 cols. grid = N/8 = 512.
template<int MODE>
__global__ void k_gemm_s(const float* __restrict__ src, const float* __restrict__ dis,
                         const float* __restrict__ p, const float* __restrict__ q,
                         const float* __restrict__ mbv, const float* __restrict__ lbv,
                         const float* __restrict__ mav, const float* __restrict__ lav,
                         const float* __restrict__ u, float* __restrict__ s){
  constexpr int TK = 128;
  __shared__ float cs[8][TK + 4];          // stride 132 floats: 16B-aligned rows
  int tid  = threadIdx.x;
  int row0 = blockIdx.x * 8;
  int tx = tid & 63;                        // column (and +64)
  int ty = tid >> 6;                        // 0..3 -> rows ty*2+{0,1}
  int lrow = tid >> 5;                      // loader row 0..7
  int lk4  = tid & 31;                      // loader float4-chunk 0..31
  int grow = row0 + lrow;
  float mrow = mbv[grow];
  float rl   = 1.0f / lbv[grow];
  float dif = (MODE == 0) ? dis[grow] : 0.f;
  float pi = 0.f, mar = 0.f, rla = 0.f;
  if (MODE == 2){ pi = p[grow]; mar = mav[grow]; rla = 1.0f / lav[grow]; }
  float acc[2][2];
  acc[0][0] = acc[0][1] = acc[1][0] = acc[1][1] = 0.f;
  const float* srow = src + (size_t)grow * N;

  for (int kt = 0; kt < N; kt += TK){
    float4 a = *reinterpret_cast<const float4*>(srow + kt + lk4 * 4);
    float c0, c1, c2, c3;
    if (MODE == 0){
      float4 dj = *reinterpret_cast<const float4*>(dis + kt + lk4 * 4);
      c0 = a.x * (dif * dj.x); c1 = a.y * (dif * dj.y);
      c2 = a.z * (dif * dj.z); c3 = a.w * (dif * dj.w);
    } else { c0 = a.x; c1 = a.y; c2 = a.z; c3 = a.w; }
    c0 = expf(c0 - mrow) * rl; c1 = expf(c1 - mrow) * rl;
    c2 = expf(c2 - mrow) * rl; c3 = expf(c3 - mrow) * rl;
    if (MODE == 2){
      float4 qq = *reinterpret_cast<const float4*>(q + kt + lk4 * 4);
      c0 = 0.6f * c0 + 0.4f * expf(lrelu(pi + qq.x) - mar) * rla;
      c1 = 0.6f * c1 + 0.4f * expf(lrelu(pi + qq.y) - mar) * rla;
      c2 = 0.6f * c2 + 0.4f * expf(lrelu(pi + qq.z) - mar) * rla;
      c3 = 0.6f * c3 + 0.4f * expf(lrelu(pi + qq.w) - mar) * rla;
    }
    __syncthreads();
    float4 cc; cc.x = c0; cc.y = c1; cc.z = c2; cc.w = c3;
    *reinterpret_cast<float4*>(&cs[lrow][lk4 * 4]) = cc;
    __syncthreads();

    const float* ub = u + (size_t)kt * D;
    #pragma unroll 8
    for (int k4 = 0; k4 < TK / 4; ++k4){
      float u0[4], u1[4];
      #pragma unroll
      for (int j = 0; j < 4; ++j){
        u0[j] = ub[(size_t)(k4 * 4 + j) * D + tx];
        u1[j] = ub[(size_t)(k4 * 4 + j) * D + tx + 64];
      }
      #pragma unroll
      for (int m = 0; m < 2; ++m){
        float4 c4 = *reinterpret_cast<const float4*>(&cs[ty * 2 + m][k4 * 4]);
        acc[m][0] = fmaf(c4.x, u0[0], fmaf(c4.y, u0[1], fmaf(c4.z, u0[2], fmaf(c4.w, u0[3], acc[m][0]))));
        acc[m][1] = fmaf(c4.x, u1[0], fmaf(c4.y, u1[1], fmaf(c4.z, u1[2], fmaf(c4.w, u1[3], acc[m][1]))));
      }
    }
  }
  #pragma unroll
  for (int m = 0; m < 2; ++m){
    size_t r = (size_t)(row0 + ty * 2 + m) * D;
    s[r + tx]      = acc[m][0];
    s[r + tx + 64] = acc[m][1];
  }
}

// v = squash(s) rowwise (128 dims). Block = 128 threads.
__global__ void k_squash(const float* __restrict__ s, float* __restrict__ out){
  int i = blockIdx.x, t = threadIdx.x;
  __shared__ float red[2];
  float v = s[(size_t)i * D + t];
  float ss = wave_sum(v * v);
  if ((t & 63) == 0) red[t >> 6] = ss;
  __syncthreads();
  float tot = red[0] + red[1];
  float n = sqrtf(tot);
  float f = n / ((1.0f + n) * (n + EPSV));
  out[(size_t)i * D + t] = v * f;
}

// b-update: FIRST: b = d_i d_j adj + v @ u^T ; else b += v @ u^T
// Block 256, tile 64x64, grid 4096.
template<bool FIRST>
__global__ void k_bupd(const float* __restrict__ v, const float* __restrict__ u,
                       const float* __restrict__ adj, const float* __restrict__ dis,
                       float* __restrict__ b){
  constexpr int TK = 64;
  __shared__ float vs[64][TK + 4];   // stride 68: 16B-aligned rows
  __shared__ float us[64][TK + 4];
  int tid = threadIdx.x;
  int bx = blockIdx.x & 63, by = blockIdx.x >> 6;
  int row0 = by * 64, col0 = bx * 64;
  int tx = tid & 31;                 // col pair (tx, tx+32)
  int ty = tid >> 5;                 // 0..7 -> rows ty*8+m
  float acc[8][2];
  #pragma unroll
  for (int m = 0; m < 8; ++m){ acc[m][0] = 0.f; acc[m][1] = 0.f; }

  for (int kt = 0; kt < D; kt += TK){
    __syncthreads();
    #pragma unroll
    for (int l = 0; l < 4; ++l){
      int idx = tid + l * 256;       // 0..1023 float4 slots
      int r  = idx >> 4;             // 0..63
      int k4 = idx & 15;             // 0..15
      float4 a = *reinterpret_cast<const float4*>(v + (size_t)(row0 + r) * D + kt + k4 * 4);
      *reinterpret_cast<float4*>(&vs[r][k4 * 4]) = a;
      float4 c = *reinterpret_cast<const float4*>(u + (size_t)(col0 + r) * D + kt + k4 * 4);
      *reinterpret_cast<float4*>(&us[r][k4 * 4]) = c;
    }
    __syncthreads();
    #pragma unroll 4
    for (int k4 = 0; k4 < TK / 4; ++k4){
      float4 u0 = *reinterpret_cast<const float4*>(&us[tx][k4 * 4]);
      float4 u1 = *reinterpret_cast<const float4*>(&us[tx + 32][k4 * 4]);
      #pragma unroll
      for (int m = 0; m < 8; ++m){
        float4 vv = *reinterpret_cast<const float4*>(&vs[ty * 8 + m][k4 * 4]);
        acc[m][0] = fmaf(vv.x, u0.x, fmaf(vv.y, u0.y, fmaf(vv.z, u0.z, fmaf(vv.w, u0.w, acc[m][0]))));
        acc[m][1] = fmaf(vv.x, u1.x, fmaf(vv.y, u1.y, fmaf(vv.z, u1.z, fmaf(vv.w, u1.w, acc[m][1]))));
      }
    }
  }
  float dc0 = 0.f, dc1 = 0.f;
  if (FIRST){ dc0 = dis[col0 + tx]; dc1 = dis[col0 + tx + 32]; }
  #pragma unroll
  for (int m = 0; m < 8; ++m){
    int row = row0 + ty * 8 + m;
    size_t idx = (size_t)row * N + col0 + tx;
    if (FIRST){
      float dr = dis[row];
      b[idx]      = fmaf(adj[idx],      dr * dc0, acc[m][0]);
      b[idx + 32] = fmaf(adj[idx + 32], dr * dc1, acc[m][1]);
    } else {
      b[idx]      += acc[m][0];
      b[idx + 32] += acc[m][1];
    }
  }
}

extern "C" void kernel_launch(void* const* d_in, const int* in_sizes, int n_in,
                              void* d_out, int out_size, void* d_ws, size_t ws_size,
                              hipStream_t stream) {
  const float* h   = (const float*)d_in[0];
  const float* adj = (const float*)d_in[1];
  const float* W   = (const float*)d_in[2];
  const float* aa  = (const float*)d_in[3];
  float* out = (float*)d_out;
  float* ws  = (float*)d_ws;

  float* dis = ws;                 // 4096
  float* p   = ws + 4096;
  float* q   = ws + 8192;
  float* mb  = ws + 12288;
  float* lb  = ws + 16384;
  float* ma  = ws + 20480;
  float* la  = ws + 24576;
  float* u   = ws + 32768;         // 524288
  float* s   = u + (size_t)N * D;  // 524288
  float* v   = s + (size_t)N * D;  // 524288
  float* b   = v + (size_t)N * D;  // 16777216

  k_rowsum<<<N, 256, 0, stream>>>(adj, dis);
  k_uhat<<<N, 128, 0, stream>>>(h, W, aa, u, p, q);

  // it 0: c1 = softmax(adj_norm); v1 = squash(c1 @ u)
  k_stats<0><<<N, 256, 0, stream>>>(adj, dis, p, q, mb, lb, ma, la);
  k_gemm_s<0><<<N / 8, 256, 0, stream>>>(adj, dis, p, q, mb, lb, ma, la, u, s);
  k_squash<<<N, 128, 0, stream>>>(s, v);
  // b1 = adj_norm + v1 @ u^T
  k_bupd<true><<<4096, 256, 0, stream>>>(v, u, adj, dis, b);

  // it 1: c2 = softmax(b1); v2 = squash(c2 @ u)
  k_stats<1><<<N, 256, 0, stream>>>(b, dis, p, q, mb, lb, ma, la);
  k_gemm_s<1><<<N / 8, 256, 0, stream>>>(b, dis, p, q, mb, lb, ma, la, u, s);
  k_squash<<<N, 128, 0, stream>>>(s, v);
  // b2 = b1 + v2 @ u^T
  k_bupd<false><<<4096, 256, 0, stream>>>(v, u, adj, dis, b);

  // it 2 + final: combined = 0.6*softmax(b2) + 0.4*softmax(attn); out = squash(combined @ u)
  k_stats<2><<<N, 256, 0, stream>>>(b, dis, p, q, mb, lb, ma, la);
  k_gemm_s<2><<<N / 8, 256, 0, stream>>>(b, dis, p, q, mb, lb, ma, la, u, s);
  k_squash<<<N, 128, 0, stream>>>(s, out);
}

// Round 3
// 479.434 us; speedup vs baseline: 1.5886x; 1.5886x over previous
//
#include <hip/hip_runtime.h>
#include <math.h>

#define N 4096
#define D 128
#define EPSV 1e-8f
#define TK 32

__device__ __forceinline__ float lrelu(float x){ return x > 0.f ? x : 0.2f*x; }

__device__ __forceinline__ float wave_sum(float v){
  #pragma unroll
  for (int off = 32; off; off >>= 1) v += __shfl_down(v, off);
  return v;
}
__device__ __forceinline__ float wave_max(float v){
  #pragma unroll
  for (int off = 32; off; off >>= 1) v = fmaxf(v, __shfl_down(v, off));
  return v;
}
__device__ __forceinline__ float block_sum256(float v, float* red){
  v = wave_sum(v);
  if ((threadIdx.x & 63) == 0) red[threadIdx.x >> 6] = v;
  __syncthreads();
  float r = (red[0] + red[1]) + (red[2] + red[3]);
  __syncthreads();
  return r;
}
__device__ __forceinline__ float block_max256(float v, float* red){
  v = wave_max(v);
  if ((threadIdx.x & 63) == 0) red[threadIdx.x >> 6] = v;
  __syncthreads();
  float r = fmaxf(fmaxf(red[0], red[1]), fmaxf(red[2], red[3]));
  __syncthreads();
  return r;
}

// dis[i] = 1/sqrt(sum_j adj[i][j] + 1e-8)
__global__ void k_rowsum(const float* __restrict__ adj, float* __restrict__ dis){
  int i = blockIdx.x;
  const float4* row = reinterpret_cast<const float4*>(adj + (size_t)i * N);
  float s = 0.f;
  #pragma unroll
  for (int l = 0; l < 4; ++l){
    float4 v = row[threadIdx.x + l * 256];
    s += (v.x + v.y) + (v.z + v.w);
  }
  __shared__ float red[4];
  s = block_sum256(s, red);
  if (threadIdx.x == 0) dis[i] = 1.0f / sqrtf(s + EPSV);
}

// u = h @ W ; p = h @ a_src ; q = h @ a_dst   (block = 128 threads, one row)
__global__ void k_uhat(const float* __restrict__ h, const float* __restrict__ W,
                       const float* __restrict__ aa, float* __restrict__ u,
                       float* __restrict__ p, float* __restrict__ q){
  int i = blockIdx.x, t = threadIdx.x;
  __shared__ float hs[D];
  __shared__ float red[4];
  float hv = h[(size_t)i * D + t];
  hs[t] = hv;
  __syncthreads();
  float acc = 0.f;
  #pragma unroll 8
  for (int k = 0; k < D; ++k) acc = fmaf(hs[k], W[k * D + t], acc);
  u[(size_t)i * D + t] = acc;
  float pv = hv * aa[t];
  float qv = hv * aa[D + t];
  pv = wave_sum(pv); qv = wave_sum(qv);
  if ((t & 63) == 0){ red[t >> 6] = pv; red[2 + (t >> 6)] = qv; }
  __syncthreads();
  if (t == 0){ p[i] = red[0] + red[1]; q[i] = red[2] + red[3]; }
}

// Row max + sum(exp) stats. MODE 0: src=adj with d_i d_j norm. MODE 1: src=b.
// MODE 2: src=b, plus attention-row stats from p,q.
template<int MODE>
__global__ void k_stats(const float* __restrict__ src, const float* __restrict__ dis,
                        const float* __restrict__ pv, const float* __restrict__ qv,
                        float* __restrict__ mb, float* __restrict__ lb,
                        float* __restrict__ ma, float* __restrict__ la){
  __shared__ float red[4];
  int i = blockIdx.x;
  const float4* src4 = reinterpret_cast<const float4*>(src + (size_t)i * N);
  const float4* dis4 = reinterpret_cast<const float4*>(dis);
  const float4* q4   = reinterpret_cast<const float4*>(qv);
  float di = (MODE == 0) ? dis[i] : 0.f;
  float pi = (MODE == 2) ? pv[i] : 0.f;
  float4 vals[4];
  float mx = -3.4e38f, amx = -3.4e38f;
  #pragma unroll
  for (int l = 0; l < 4; ++l){
    int t = threadIdx.x + l * 256;
    float4 a = src4[t];
    if (MODE == 0){
      float4 dj = dis4[t];
      a.x *= di * dj.x; a.y *= di * dj.y; a.z *= di * dj.z; a.w *= di * dj.w;
    }
    vals[l] = a;
    mx = fmaxf(mx, fmaxf(fmaxf(a.x, a.y), fmaxf(a.z, a.w)));
    if (MODE == 2){
      float4 qq = q4[t];
      float a0 = lrelu(pi + qq.x), a1 = lrelu(pi + qq.y);
      float a2 = lrelu(pi + qq.z), a3 = lrelu(pi + qq.w);
      amx = fmaxf(amx, fmaxf(fmaxf(a0, a1), fmaxf(a2, a3)));
    }
  }
  float m = block_max256(mx, red);
  float se = 0.f;
  #pragma unroll
  for (int l = 0; l < 4; ++l){
    float4 a = vals[l];
    se += expf(a.x - m) + expf(a.y - m) + expf(a.z - m) + expf(a.w - m);
  }
  float ls = block_sum256(se, red);
  if (MODE == 2){
    float am = block_max256(amx, red);
    float ase = 0.f;
    #pragma unroll
    for (int l = 0; l < 4; ++l){
      int t = threadIdx.x + l * 256;
      float4 qq = q4[t];
      ase += expf(lrelu(pi + qq.x) - am) + expf(lrelu(pi + qq.y) - am)
           + expf(lrelu(pi + qq.z) - am) + expf(lrelu(pi + qq.w) - am);
    }
    float al = block_sum256(ase, red);
    if (threadIdx.x == 0){ ma[i] = am; la[i] = al; }
  }
  if (threadIdx.x == 0){ mb[i] = m; lb[i] = ls; }
}

// ---------------------------------------------------------------------------
// s_part[y][i][n] = sum_{j in K-split y} softmax_row(i)[j] * u[j][n]
// Block tile: 128 rows x 128 cols (full N), thread tile 8x8, TK=32, LDS-staged.
// A is transposed to k-major during staging with the softmax fused in.
// grid = (32, KS); kRange = N/KS.
// ---------------------------------------------------------------------------
template<int MODE>
__global__ __launch_bounds__(256)
void k_gemm2(const float* __restrict__ src, const float* __restrict__ dis,
             const float* __restrict__ p, const float* __restrict__ q,
             const float* __restrict__ mbv, const float* __restrict__ lbv,
             const float* __restrict__ mav, const float* __restrict__ lav,
             const float* __restrict__ u, float* __restrict__ s_part, int kRange){
  __shared__ float As[TK][132];   // 132 floats = 528 B rows (16B-aligned)
  __shared__ float Bs[TK][132];
  const int tid  = threadIdx.x;
  const int row0 = blockIdx.x * 128;
  const int k0   = blockIdx.y * kRange;
  const int ty4  = (tid >> 4) * 4;   // row offset within tile
  const int tx4  = (tid & 15) * 4;   // col offset within tile
  const int lr   = tid >> 3;         // loader row base 0..31
  const int lk   = (tid & 7) * 4;    // loader k chunk 0..28

  float mrow[4], rl[4], dif[4], pi[4], mar[4], rla[4];
  #pragma unroll
  for (int l = 0; l < 4; ++l){
    int r = row0 + lr + l * 32;
    mrow[l] = mbv[r]; rl[l] = 1.0f / lbv[r];
    dif[l] = (MODE == 0) ? dis[r] : 0.f;
    if (MODE == 2){ pi[l] = p[r]; mar[l] = mav[r]; rla[l] = 1.0f / lav[r]; }
    else { pi[l] = 0.f; mar[l] = 0.f; rla[l] = 0.f; }
  }

  float acc[2][2][4][4] = {};   // [rowblk][colblk][i][j]

  for (int kt = 0; kt < kRange; kt += TK){
    const int kb = k0 + kt;
    __syncthreads();
    // stage B (u rows kb..kb+31) — direct copy, float4, conflict-free
    #pragma unroll
    for (int l = 0; l < 4; ++l){
      int idx = tid + l * 256;
      int k = idx >> 5;
      int c = (idx & 31) * 4;
      float4 bv = *reinterpret_cast<const float4*>(u + (size_t)(kb + k) * D + c);
      *reinterpret_cast<float4*>(&Bs[k][c]) = bv;
    }
    // stage A (softmax(src) rows row0..row0+127, k kb..kb+31), transposed
    #pragma unroll
    for (int l = 0; l < 4; ++l){
      int r = lr + l * 32;
      float4 a = *reinterpret_cast<const float4*>(src + (size_t)(row0 + r) * N + kb + lk);
      float c0, c1, c2, c3;
      if (MODE == 0){
        float4 dj = *reinterpret_cast<const float4*>(dis + kb + lk);
        c0 = a.x * dif[l] * dj.x; c1 = a.y * dif[l] * dj.y;
        c2 = a.z * dif[l] * dj.z; c3 = a.w * dif[l] * dj.w;
      } else { c0 = a.x; c1 = a.y; c2 = a.z; c3 = a.w; }
      c0 = __expf(c0 - mrow[l]) * rl[l]; c1 = __expf(c1 - mrow[l]) * rl[l];
      c2 = __expf(c2 - mrow[l]) * rl[l]; c3 = __expf(c3 - mrow[l]) * rl[l];
      if (MODE == 2){
        float4 qq = *reinterpret_cast<const float4*>(q + kb + lk);
        c0 = 0.6f * c0 + 0.4f * __expf(lrelu(pi[l] + qq.x) - mar[l]) * rla[l];
        c1 = 0.6f * c1 + 0.4f * __expf(lrelu(pi[l] + qq.y) - mar[l]) * rla[l];
        c2 = 0.6f * c2 + 0.4f * __expf(lrelu(pi[l] + qq.z) - mar[l]) * rla[l];
        c3 = 0.6f * c3 + 0.4f * __expf(lrelu(pi[l] + qq.w) - mar[l]) * rla[l];
      }
      As[lk + 0][r] = c0; As[lk + 1][r] = c1;
      As[lk + 2][r] = c2; As[lk + 3][r] = c3;
    }
    __syncthreads();

    #pragma unroll 8
    for (int k = 0; k < TK; ++k){
      float4 a0 = *reinterpret_cast<const float4*>(&As[k][ty4]);
      float4 a1 = *reinterpret_cast<const float4*>(&As[k][ty4 + 64]);
      float4 b0 = *reinterpret_cast<const float4*>(&Bs[k][tx4]);
      float4 b1 = *reinterpret_cast<const float4*>(&Bs[k][tx4 + 64]);
      float ar[2][4] = {{a0.x, a0.y, a0.z, a0.w}, {a1.x, a1.y, a1.z, a1.w}};
      float br[2][4] = {{b0.x, b0.y, b0.z, b0.w}, {b1.x, b1.y, b1.z, b1.w}};
      #pragma unroll
      for (int rb = 0; rb < 2; ++rb)
        #pragma unroll
        for (int i = 0; i < 4; ++i)
          #pragma unroll
          for (int cb = 0; cb < 2; ++cb)
            #pragma unroll
            for (int j = 0; j < 4; ++j)
              acc[rb][cb][i][j] = fmaf(ar[rb][i], br[cb][j], acc[rb][cb][i][j]);
    }
  }

  #pragma unroll
  for (int rb = 0; rb < 2; ++rb)
    #pragma unroll
    for (int i = 0; i < 4; ++i){
      int row = row0 + rb * 64 + ty4 + i;
      #pragma unroll
      for (int cb = 0; cb < 2; ++cb){
        float4 o;
        o.x = acc[rb][cb][i][0]; o.y = acc[rb][cb][i][1];
        o.z = acc[rb][cb][i][2]; o.w = acc[rb][cb][i][3];
        *reinterpret_cast<float4*>(
            &s_part[((size_t)blockIdx.y * N + row) * D + cb * 64 + tx4]) = o;
      }
    }
}

// sum K-split partials + squash. Block = 128 threads, one row.
__global__ void k_reduce_squash(const float* __restrict__ s_part,
                                float* __restrict__ out, int ks){
  int row = blockIdx.x, t = threadIdx.x;
  float a = 0.f;
  for (int y = 0; y < ks; ++y) a += s_part[((size_t)y * N + row) * D + t];
  __shared__ float red[2];
  float ss = wave_sum(a * a);
  if ((t & 63) == 0) red[t >> 6] = ss;
  __syncthreads();
  float tot = red[0] + red[1];
  float n = sqrtf(tot);
  float f = n / ((1.0f + n) * (n + EPSV));
  out[(size_t)row * D + t] = a * f;
}

// ---------------------------------------------------------------------------
// b-update: FIRST: b = d_i d_j adj + v @ u^T ; else b += v @ u^T
// Block tile 128x128, thread tile 8x8, K = D = 128, TK = 32. grid = 1024.
// Both operands transposed to k-major in LDS during staging.
// ---------------------------------------------------------------------------
template<bool FIRST>
__global__ __launch_bounds__(256)
void k_bupd2(const float* __restrict__ v, const float* __restrict__ u,
             const float* __restrict__ adj, const float* __restrict__ dis,
             float* __restrict__ b){
  __shared__ float As[TK][132];
  __shared__ float Bs[TK][132];
  const int tid  = threadIdx.x;
  const int row0 = (blockIdx.x >> 5) * 128;
  const int col0 = (blockIdx.x & 31) * 128;
  const int ty4  = (tid >> 4) * 4;
  const int tx4  = (tid & 15) * 4;
  const int lr   = tid >> 3;
  const int lk   = (tid & 7) * 4;

  float acc[2][2][4][4] = {};

  for (int kt = 0; kt < D; kt += TK){
    __syncthreads();
    #pragma unroll
    for (int l = 0; l < 4; ++l){
      int r = lr + l * 32;
      float4 a = *reinterpret_cast<const float4*>(v + (size_t)(row0 + r) * D + kt + lk);
      As[lk + 0][r] = a.x; As[lk + 1][r] = a.y;
      As[lk + 2][r] = a.z; As[lk + 3][r] = a.w;
      float4 c = *reinterpret_cast<const float4*>(u + (size_t)(col0 + r) * D + kt + lk);
      Bs[lk + 0][r] = c.x; Bs[lk + 1][r] = c.y;
      Bs[lk + 2][r] = c.z; Bs[lk + 3][r] = c.w;
    }
    __syncthreads();

    #pragma unroll 8
    for (int k = 0; k < TK; ++k){
      float4 a0 = *reinterpret_cast<const float4*>(&As[k][ty4]);
      float4 a1 = *reinterpret_cast<const float4*>(&As[k][ty4 + 64]);
      float4 b0 = *reinterpret_cast<const float4*>(&Bs[k][tx4]);
      float4 b1 = *reinterpret_cast<const float4*>(&Bs[k][tx4 + 64]);
      float ar[2][4] = {{a0.x, a0.y, a0.z, a0.w}, {a1.x, a1.y, a1.z, a1.w}};
      float br[2][4] = {{b0.x, b0.y, b0.z, b0.w}, {b1.x, b1.y, b1.z, b1.w}};
      #pragma unroll
      for (int rb = 0; rb < 2; ++rb)
        #pragma unroll
        for (int i = 0; i < 4; ++i)
          #pragma unroll
          for (int cb = 0; cb < 2; ++cb)
            #pragma unroll
            for (int j = 0; j < 4; ++j)
              acc[rb][cb][i][j] = fmaf(ar[rb][i], br[cb][j], acc[rb][cb][i][j]);
    }
  }

  float4 dc[2];
  if (FIRST){
    dc[0] = *reinterpret_cast<const float4*>(dis + col0 + tx4);
    dc[1] = *reinterpret_cast<const float4*>(dis + col0 + 64 + tx4);
  }
  #pragma unroll
  for (int rb = 0; rb < 2; ++rb)
    #pragma unroll
    for (int i = 0; i < 4; ++i){
      int row = row0 + rb * 64 + ty4 + i;
      float dr = FIRST ? dis[row] : 0.f;
      #pragma unroll
      for (int cb = 0; cb < 2; ++cb){
        size_t idx = (size_t)row * N + col0 + cb * 64 + tx4;
        float4 o;
        if (FIRST){
          float4 ad = *reinterpret_cast<const float4*>(adj + idx);
          o.x = fmaf(ad.x, dr * dc[cb].x, acc[rb][cb][i][0]);
          o.y = fmaf(ad.y, dr * dc[cb].y, acc[rb][cb][i][1]);
          o.z = fmaf(ad.z, dr * dc[cb].z, acc[rb][cb][i][2]);
          o.w = fmaf(ad.w, dr * dc[cb].w, acc[rb][cb][i][3]);
        } else {
          float4 bo = *reinterpret_cast<const float4*>(b + idx);
          o.x = bo.x + acc[rb][cb][i][0];
          o.y = bo.y + acc[rb][cb][i][1];
          o.z = bo.z + acc[rb][cb][i][2];
          o.w = bo.w + acc[rb][cb][i][3];
        }
        *reinterpret_cast<float4*>(b + idx) = o;
      }
    }
}

extern "C" void kernel_launch(void* const* d_in, const int* in_sizes, int n_in,
                              void* d_out, int out_size, void* d_ws, size_t ws_size,
                              hipStream_t stream) {
  const float* h   = (const float*)d_in[0];
  const float* adj = (const float*)d_in[1];
  const float* W   = (const float*)d_in[2];
  const float* aa  = (const float*)d_in[3];
  float* out = (float*)d_out;
  float* ws  = (float*)d_ws;

  float* dis = ws;                 // 4096
  float* p   = ws + 4096;
  float* q   = ws + 8192;
  float* mb  = ws + 12288;
  float* lb  = ws + 16384;
  float* ma  = ws + 20480;
  float* la  = ws + 24576;
  float* u   = ws + 32768;            // 524288 floats
  float* v   = u + (size_t)N * D;     // 524288
  float* b   = v + (size_t)N * D;     // 16777216
  float* s_part = b + (size_t)N * N;  // KS * 524288

  // Choose K-split by available workspace (each split slab = 2 MB).
  size_t base_floats = (size_t)(s_part - ws);
  int KS = 16;
  while (KS > 1 && (base_floats + (size_t)KS * N * D) * 4 > ws_size) KS >>= 1;
  int kRange = N / KS;
  dim3 gg(32, KS);

  k_rowsum<<<N, 256, 0, stream>>>(adj, dis);
  k_uhat<<<N, 128, 0, stream>>>(h, W, aa, u, p, q);

  // it 0: c1 = softmax(adj_norm); v1 = squash(c1 @ u)
  k_stats<0><<<N, 256, 0, stream>>>(adj, dis, p, q, mb, lb, ma, la);
  k_gemm2<0><<<gg, 256, 0, stream>>>(adj, dis, p, q, mb, lb, ma, la, u, s_part, kRange);
  k_reduce_squash<<<N, 128, 0, stream>>>(s_part, v, KS);
  // b1 = adj_norm + v1 @ u^T
  k_bupd2<true><<<1024, 256, 0, stream>>>(v, u, adj, dis, b);

  // it 1: c2 = softmax(b1); v2 = squash(c2 @ u)
  k_stats<1><<<N, 256, 0, stream>>>(b, dis, p, q, mb, lb, ma, la);
  k_gemm2<1><<<gg, 256, 0, stream>>>(b, dis, p, q, mb, lb, ma, la, u, s_part, kRange);
  k_reduce_squash<<<N, 128, 0, stream>>>(s_part, v, KS);
  // b2 = b1 + v2 @ u^T
  k_bupd2<false><<<1024, 256, 0, stream>>>(v, u, adj, dis, b);

  // it 2 + final: combined = 0.6*softmax(b2) + 0.4*softmax(attn); out = squash(combined @ u)
  k_stats<2><<<N, 256, 0, stream>>>(b, dis, p, q, mb, lb, ma, la);
  k_gemm2<2><<<gg, 256, 0, stream>>>(b, dis, p, q, mb, lb, ma, la, u, s_part, kRange);
  k_reduce_squash<<<N, 128, 0, stream>>>(s_part, out, KS);
}